// Round 10
// baseline (175.288 us; speedup 1.0000x reference)
//
#include <hip/hip_runtime.h>
#include <hip/hip_bf16.h>

#define DEVINL __device__ __forceinline__

typedef short s16x8 __attribute__((ext_vector_type(8)));
typedef float f32x4 __attribute__((ext_vector_type(4)));

static constexpr int TC = 1024;      // d_model
static constexpr int NH = 16;        // heads
static constexpr int DH = 64;        // head dim
static constexpr int TT = 2048;      // seq len
static constexpr int NB = 4;         // batch
static constexpr int MROWS = NB * TT;  // 8192

// fold 1/sqrt(Dh) * log2(e) into Q so softmax can use exp2 (v_exp_f32)
static constexpr float QSCALE = 0.18033688011112042f;  // 0.125 * 1.4426950408889634

DEVINL ushort f32_to_bf16u(float f) {
  uint u = __builtin_bit_cast(uint, f);
  u += 0x7fffu + ((u >> 16) & 1u);   // round-to-nearest-even
  return (ushort)(u >> 16);
}

DEVINL f32x4 mfma32(s16x8 a, s16x8 b, f32x4 c) {
  return __builtin_amdgcn_mfma_f32_16x16x32_bf16(a, b, c, 0, 0, 0);
}

DEVINL void gload_lds16(const void* g, void* l) {
  __builtin_amdgcn_global_load_lds((const __attribute__((address_space(1))) void*)g,
                                   (__attribute__((address_space(3))) void*)l, 16, 0, 0);
}

DEVINL s16x8 ld8(const ushort* p) { return *reinterpret_cast<const s16x8*>(p); }

// ---------------- fp32 -> bf16 convert: all three tensors, one launch ----------------
DEVINL void cvt_range(const float* __restrict__ src, ushort* __restrict__ dst, int n4,
                      int i0, int stride) {
  for (int i = i0; i < n4; i += stride) {
    float4 v = reinterpret_cast<const float4*>(src)[i];
    ushort4 o;
    o.x = f32_to_bf16u(v.x);
    o.y = f32_to_bf16u(v.y);
    o.z = f32_to_bf16u(v.z);
    o.w = f32_to_bf16u(v.w);
    reinterpret_cast<ushort4*>(dst)[i] = o;
  }
}

__global__ void cvt3_kernel(const float* __restrict__ s0, ushort* __restrict__ d0, int n0,
                            const float* __restrict__ s1, ushort* __restrict__ d1, int n1,
                            const float* __restrict__ s2, ushort* __restrict__ d2, int n2) {
  const int i0 = blockIdx.x * blockDim.x + threadIdx.x;
  const int stride = gridDim.x * blockDim.x;
  cvt_range(s0, d0, n0, i0, stride);
  cvt_range(s1, d1, n1, i0, stride);
  cvt_range(s2, d2, n2, i0, stride);
}

// ---------------- GEMM: C[M,N] = A[M,K] * B[N,K]^T, K = 1024 ----------------
// Round-10: CLEAN 2-phase retest (round-6 was confounded by XCD swizzle).
// BK=64, double-buffered (2x32KB = 64KB LDS, SAME footprint as the round-8
// BK=128 single-buffer winner -> occupancy unchanged at 2 blocks/CU).
// T3-minimum: GSTAGE(t+1) issued BEFORE compute(t); ONE barrier per tile —
// its vmcnt-drain lands after 32 MFMAs of compute instead of immediately.
// Swizzle f(r)=r&7, pre-swizzled source / linear dest / swizzled read.
template <int MODE>
__global__ __launch_bounds__(256, 2) void gemm_bt(
    const ushort* __restrict__ A, const ushort* __restrict__ Bw, float* __restrict__ Cout,
    ushort* __restrict__ Qo, ushort* __restrict__ Ko, ushort* __restrict__ Vo, int N) {
  __shared__ __align__(16) ushort As[2][128 * 64];
  __shared__ __align__(16) ushort Bs[2][128 * 64];
  const int tid = threadIdx.x;
  const int lane = tid & 63;
  const int wid = tid >> 6;
  const int bx = blockIdx.x, by = blockIdx.y;
  const int wrow = (wid >> 1) * 64, wcol = (wid & 1) * 64;
  const int lr = lane >> 3;
  const int lc = lane & 7;

  f32x4 acc[4][4] = {};

#define GSTAGE(buf, kt)                                                         \
  {                                                                             \
    _Pragma("unroll") for (int j = 0; j < 4; ++j) {                             \
      const int seg = wid * 4 + j;                                              \
      const int r = seg * 8 + lr;                                               \
      const int csrc = lc ^ (r & 7);                                            \
      gload_lds16(A + (size_t)(by * 128 + r) * TC + (kt) + csrc * 8,            \
                  &As[buf][seg * 512]);                                         \
      gload_lds16(Bw + (size_t)(bx * 128 + r) * TC + (kt) + csrc * 8,           \
                  &Bs[buf][seg * 512]);                                         \
    }                                                                           \
  }

  GSTAGE(0, 0);
  __syncthreads();

  for (int t = 0; t < TC / 64; ++t) {
    const int buf = t & 1;
    if (t + 1 < TC / 64) GSTAGE(buf ^ 1, (t + 1) * 64);  // prefetch BEFORE compute
#pragma unroll
    for (int kk = 0; kk < 2; ++kk) {
      s16x8 af[4], bfr[4];
#pragma unroll
      for (int m = 0; m < 4; ++m) {
        const int r = wrow + m * 16 + (lane & 15);
        const int ch = (kk * 4 + (lane >> 4)) ^ (r & 7);  // swizzled read
        af[m] = ld8(&As[buf][r * 64 + ch * 8]);
      }
#pragma unroll
      for (int n = 0; n < 4; ++n) {
        const int r = wcol + n * 16 + (lane & 15);
        const int ch = (kk * 4 + (lane >> 4)) ^ (r & 7);
        bfr[n] = ld8(&Bs[buf][r * 64 + ch * 8]);
      }
#pragma unroll
      for (int m = 0; m < 4; ++m)
#pragma unroll
        for (int n = 0; n < 4; ++n) acc[m][n] = mfma32(af[m], bfr[n], acc[m][n]);
    }
    __syncthreads();  // single barrier/tile: drains prefetch after 32 MFMAs
  }
#undef GSTAGE

#pragma unroll
  for (int m = 0; m < 4; ++m) {
#pragma unroll
    for (int n = 0; n < 4; ++n) {
      const int ng = bx * 128 + wcol + n * 16 + (lane & 15);
      const int mg0 = by * 128 + wrow + m * 16 + (lane >> 4) * 4;
      if (MODE == 0) {
#pragma unroll
        for (int i = 0; i < 4; ++i) Cout[(size_t)(mg0 + i) * N + ng] = acc[m][n][i];
      } else {
        const int sec = ng >> 10;            // 0=Q 1=K 2=V (uniform per fragment)
        const int w = ng & 1023;
        const int h = w >> 6, d = w & 63;
        const int t0 = mg0 & (TT - 1);       // mg0 % 4 == 0 -> 4 consecutive t
        const int b = mg0 >> 11;
        const int bh = b * NH + h;
        if (sec == 0) {
#pragma unroll
          for (int i = 0; i < 4; ++i)
            Qo[((size_t)bh * TT + t0 + i) * DH + d] = f32_to_bf16u(acc[m][n][i] * QSCALE);
        } else if (sec == 1) {
#pragma unroll
          for (int i = 0; i < 4; ++i)
            Ko[((size_t)bh * TT + t0 + i) * DH + d] = f32_to_bf16u(acc[m][n][i]);
        } else {
          ushort4 o;
          o.x = f32_to_bf16u(acc[m][n][0]);
          o.y = f32_to_bf16u(acc[m][n][1]);
          o.z = f32_to_bf16u(acc[m][n][2]);
          o.w = f32_to_bf16u(acc[m][n][3]);
          *reinterpret_cast<ushort4*>(&Vo[((size_t)bh * DH + d) * TT + t0]) = o;  // V^T
        }
      }
    }
  }
}

// ---------------- flash attention v7 (FROZEN): cvt_pk P-pack ----------------
__global__ __launch_bounds__(256, 4) void attn_kernel(const ushort* __restrict__ Q,
                                                      const ushort* __restrict__ K,
                                                      const ushort* __restrict__ V,
                                                      ushort* __restrict__ O) {
  __shared__ __align__(16) ushort Ks[2][64 * 64];
  __shared__ __align__(16) ushort Vs[2][64 * 64];
  const int tid = threadIdx.x;
  const int lane = tid & 63, wid = tid >> 6;
  const int bh = blockIdx.x;
  const int q0 = blockIdx.y * 128 + wid * 32;
  const int qr = lane & 15, lg = lane >> 4;

  const ushort* Qh = Q + (size_t)bh * TT * DH;
  const ushort* Kh = K + (size_t)bh * TT * DH;
  const ushort* Vh = V + (size_t)bh * DH * TT;

  s16x8 qf[2][2];
#pragma unroll
  for (int qt = 0; qt < 2; ++qt)
#pragma unroll
    for (int h = 0; h < 2; ++h)
      qf[qt][h] = ld8(&Qh[(q0 + qt * 16 + qr) * DH + h * 32 + lg * 8]);

  const int pk = 8 * (qr >> 2) + (qr & 3);  // key-row permutation

  const uint one_bf = 0x3F803F80u;
  const s16x8 ONES = __builtin_bit_cast(s16x8, (uint4){one_bf, one_bf, one_bf, one_bf});

  f32x4 acc[2][4] = {};
  f32x4 acc1[2] = {};            // row-sum accumulator (denominator)

#define SWZ(r) ((r ^ ((r & 8) >> 1)) & 7)

  // hoisted LDS fragment offsets (fully unrolled -> registers, static indexing)
  int koff[2][2][2], voff[2][4];
#pragma unroll
  for (int kh = 0; kh < 2; ++kh) {
#pragma unroll
    for (int jj = 0; jj < 2; ++jj)
#pragma unroll
      for (int h = 0; h < 2; ++h) {
        const int r = kh * 32 + pk + 4 * jj;
        koff[kh][jj][h] = r * 64 + ((h * 4 + lg) ^ SWZ(r)) * 8;
      }
#pragma unroll
    for (int g = 0; g < 4; ++g) {
      const int r = g * 16 + qr;
      voff[kh][g] = r * 64 + ((kh * 4 + lg) ^ SWZ(r)) * 8;
    }
  }

  // stage 64-key K and V^T tiles; pre-swizzled global source, linear LDS dest
#define STAGE(buf, k0)                                                              \
  {                                                                                 \
    _Pragma("unroll") for (int j = 0; j < 2; ++j) {                                 \
      const int l = tid + 256 * j;                                                  \
      const int row = l >> 3, ch = l & 7;                                           \
      const int sc = ch ^ SWZ(row);                                                 \
      gload_lds16(&Kh[(size_t)((k0) + row) * DH + sc * 8],                          \
                  &Ks[buf][(wid * 64 + 256 * j) * 8]);                              \
      gload_lds16(&Vh[(size_t)row * TT + (k0) + sc * 8],                            \
                  &Vs[buf][(wid * 64 + 256 * j) * 8]);                              \
    }                                                                               \
  }

  STAGE(0, 0);
  __syncthreads();

  for (int t = 0; t < TT / 64; ++t) {
    const int buf = t & 1;
    if (t + 1 < TT / 64) STAGE(buf ^ 1, (t + 1) * 64);
    const ushort* Kb = Ks[buf];
    const ushort* Vb = Vs[buf];

#pragma unroll
    for (int kh = 0; kh < 2; ++kh) {
      s16x8 kf[2][2];
#pragma unroll
      for (int jj = 0; jj < 2; ++jj)
#pragma unroll
        for (int h = 0; h < 2; ++h) kf[jj][h] = ld8(&Kb[koff[kh][jj][h]]);
      s16x8 vf[4];
#pragma unroll
      for (int g = 0; g < 4; ++g) vf[g] = ld8(&Vb[voff[kh][g]]);

#pragma unroll
      for (int qt = 0; qt < 2; ++qt) {
        const f32x4 z = {};
        __builtin_amdgcn_s_setprio(1);
        f32x4 slo = mfma32(kf[0][0], qf[qt][0], z);
        slo = mfma32(kf[0][1], qf[qt][1], slo);
        f32x4 shi = mfma32(kf[1][0], qf[qt][0], z);
        shi = mfma32(kf[1][1], qf[qt][1], shi);
        __builtin_amdgcn_s_setprio(0);
        // lane: S[q=qr][phys key base + 8*lg + i] (slo) and +4 (shi)

        float p[8];
#pragma unroll
        for (int i = 0; i < 4; ++i) {
          p[i] = __builtin_amdgcn_exp2f(slo[i]);
          p[4 + i] = __builtin_amdgcn_exp2f(shi[i]);
        }

        // pack to bf16: v_cvt_pk_bf16_f32 (RNE), 1 op per pair
        uint u[4];
#pragma unroll
        for (int e = 0; e < 4; ++e)
          asm("v_cvt_pk_bf16_f32 %0, %1, %2" : "=v"(u[e]) : "v"(p[2 * e]), "v"(p[2 * e + 1]));
        const s16x8 pa = __builtin_bit_cast(s16x8, u);

        __builtin_amdgcn_s_setprio(1);
#pragma unroll
        for (int g = 0; g < 4; ++g) acc[qt][g] = mfma32(pa, vf[g], acc[qt][g]);
        acc1[qt] = mfma32(pa, ONES, acc1[qt]);  // denominator row-sum
        __builtin_amdgcn_s_setprio(0);
      }
    }
    __syncthreads();
  }

  const int b = bh >> 4, h = bh & 15;
#pragma unroll
  for (int qt = 0; qt < 2; ++qt) {
    float inv[4];
#pragma unroll
    for (int i = 0; i < 4; ++i) inv[i] = 1.0f / acc1[qt][i];
#pragma unroll
    for (int g = 0; g < 4; ++g) {
#pragma unroll
      for (int i = 0; i < 4; ++i) {
        const int tq = q0 + qt * 16 + lg * 4 + i;
        const int col = h * DH + g * 16 + qr;
        O[((size_t)b * TT + tq) * TC + col] = f32_to_bf16u(acc[qt][g][i] * inv[i]);
      }
    }
  }
#undef STAGE
#undef SWZ
}

// ---------------- launch ----------------
extern "C" void kernel_launch(void* const* d_in, const int* in_sizes, int n_in,
                              void* d_out, int out_size, void* d_ws, size_t ws_size,
                              hipStream_t stream) {
  const float* x = (const float*)d_in[0];
  const float* wqkv = (const float*)d_in[1];
  const float* wout = (const float*)d_in[2];
  float* out = (float*)d_out;
  char* ws = (char*)d_ws;

  // workspace layout (72 MB total); xb is dead after GEMM1 so attn output reuses it
  ushort* xb    = (ushort*)(ws);                        // 16 MB, later attn_out
  ushort* wqkvb = (ushort*)(ws + ((size_t)16 << 20));   // 6 MB
  ushort* woutb = (ushort*)(ws + ((size_t)22 << 20));   // 2 MB
  ushort* qb    = (ushort*)(ws + ((size_t)24 << 20));   // 16 MB
  ushort* kb    = (ushort*)(ws + ((size_t)40 << 20));   // 16 MB
  ushort* vtb   = (ushort*)(ws + ((size_t)56 << 20));   // 16 MB

  cvt3_kernel<<<2048, 256, 0, stream>>>(x, xb, MROWS * TC / 4,
                                        wqkv, wqkvb, 3 * TC * TC / 4,
                                        wout, woutb, TC * TC / 4);

  gemm_bt<1><<<dim3(3 * TC / 128, MROWS / 128), 256, 0, stream>>>(
      xb, wqkvb, nullptr, qb, kb, vtb, 3 * TC);

  attn_kernel<<<dim3(NB * NH, TT / 128), 256, 0, stream>>>(qb, kb, vtb, xb);

  gemm_bt<0><<<dim3(TC / 128, MROWS / 128), 256, 0, stream>>>(
      xb, woutb, out, nullptr, nullptr, nullptr, TC);
}

// Round 11
// 167.847 us; speedup vs baseline: 1.0443x; 1.0443x over previous
//
#include <hip/hip_runtime.h>
#include <hip/hip_bf16.h>

#define DEVINL __device__ __forceinline__

typedef short s16x8 __attribute__((ext_vector_type(8)));
typedef float f32x4 __attribute__((ext_vector_type(4)));

static constexpr int TC = 1024;      // d_model
static constexpr int NH = 16;        // heads
static constexpr int DH = 64;        // head dim
static constexpr int TT = 2048;      // seq len
static constexpr int NB = 4;         // batch
static constexpr int MROWS = NB * TT;  // 8192

// fold 1/sqrt(Dh) * log2(e) into Q so softmax can use exp2 (v_exp_f32)
static constexpr float QSCALE = 0.18033688011112042f;  // 0.125 * 1.4426950408889634

DEVINL ushort f32_to_bf16u(float f) {
  uint u = __builtin_bit_cast(uint, f);
  u += 0x7fffu + ((u >> 16) & 1u);   // round-to-nearest-even
  return (ushort)(u >> 16);
}

DEVINL f32x4 mfma32(s16x8 a, s16x8 b, f32x4 c) {
  return __builtin_amdgcn_mfma_f32_16x16x32_bf16(a, b, c, 0, 0, 0);
}

DEVINL void gload_lds16(const void* g, void* l) {
  __builtin_amdgcn_global_load_lds((const __attribute__((address_space(1))) void*)g,
                                   (__attribute__((address_space(3))) void*)l, 16, 0, 0);
}

DEVINL s16x8 ld8(const ushort* p) { return *reinterpret_cast<const s16x8*>(p); }

// ---------------- fp32 -> bf16 convert: all three tensors, one launch ----------------
DEVINL void cvt_range(const float* __restrict__ src, ushort* __restrict__ dst, int n4,
                      int i0, int stride) {
  for (int i = i0; i < n4; i += stride) {
    float4 v = reinterpret_cast<const float4*>(src)[i];
    ushort4 o;
    o.x = f32_to_bf16u(v.x);
    o.y = f32_to_bf16u(v.y);
    o.z = f32_to_bf16u(v.z);
    o.w = f32_to_bf16u(v.w);
    reinterpret_cast<ushort4*>(dst)[i] = o;
  }
}

__global__ void cvt3_kernel(const float* __restrict__ s0, ushort* __restrict__ d0, int n0,
                            const float* __restrict__ s1, ushort* __restrict__ d1, int n1,
                            const float* __restrict__ s2, ushort* __restrict__ d2, int n2) {
  const int i0 = blockIdx.x * blockDim.x + threadIdx.x;
  const int stride = gridDim.x * blockDim.x;
  cvt_range(s0, d0, n0, i0, stride);
  cvt_range(s1, d1, n1, i0, stride);
  cvt_range(s2, d2, n2, i0, stride);
}

// ---------------- GEMM: C[M,N] = A[M,K] * B[N,K]^T, K = 1024 ----------------
// Round-8 winner restored (BK=128 single-buffer, 64KB LDS, measured ~61us GEMM1;
// round-10 disproved 2-phase-dbuf at this shape: 68us at same LDS/occupancy).
// Round-11 single variable: T1 chunked XCD swizzle (never isolated before —
// round 6 bundled it with the dbuf occupancy regression). logical=(h%8)*cpx+h/8
// gives each XCD a contiguous tile run -> A/W panel reuse becomes L2-local.
template <int MODE>
__global__ __launch_bounds__(256, 2) void gemm_bt(
    const ushort* __restrict__ A, const ushort* __restrict__ Bw, float* __restrict__ Cout,
    ushort* __restrict__ Qo, ushort* __restrict__ Ko, ushort* __restrict__ Vo, int N) {
  __shared__ __align__(16) ushort As[128 * 128];
  __shared__ __align__(16) ushort Bs[128 * 128];
  const int tid = threadIdx.x;
  const int lane = tid & 63;
  const int wid = tid >> 6;

  // T1: chunked XCD remap (both grids are %8==0 -> bijective)
  const int nx = gridDim.x;
  const int nwg = nx * gridDim.y;
  const int orig = blockIdx.x + nx * blockIdx.y;
  const int cpx = nwg >> 3;
  const int swz = (orig & 7) * cpx + (orig >> 3);
  const int bx = swz % nx, by = swz / nx;

  const int wrow = (wid >> 1) * 64, wcol = (wid & 1) * 64;

  f32x4 acc[4][4] = {};

  for (int kt = 0; kt < TC; kt += 128) {
#pragma unroll
    for (int j = 0; j < 8; ++j) {
      const int flat = j * 256 + tid;
      const int r = flat >> 4, ch = flat & 15;
      const int sc = ch ^ (r & 15);  // inverse swizzle on the global source
      gload_lds16(A + (size_t)(by * 128 + r) * TC + kt + sc * 8, &As[flat * 8]);
      gload_lds16(Bw + (size_t)(bx * 128 + r) * TC + kt + sc * 8, &Bs[flat * 8]);
    }
    __syncthreads();
#pragma unroll
    for (int kk = 0; kk < 4; ++kk) {
      s16x8 af[4], bfr[4];
#pragma unroll
      for (int m = 0; m < 4; ++m) {
        const int r = wrow + m * 16 + (lane & 15);
        const int ch = (kk * 4 + (lane >> 4)) ^ (r & 15);  // swizzled read
        af[m] = ld8(&As[r * 128 + ch * 8]);
      }
#pragma unroll
      for (int n = 0; n < 4; ++n) {
        const int r = wcol + n * 16 + (lane & 15);
        const int ch = (kk * 4 + (lane >> 4)) ^ (r & 15);
        bfr[n] = ld8(&Bs[r * 128 + ch * 8]);
      }
#pragma unroll
      for (int m = 0; m < 4; ++m)
#pragma unroll
        for (int n = 0; n < 4; ++n) acc[m][n] = mfma32(af[m], bfr[n], acc[m][n]);
    }
    __syncthreads();
  }

#pragma unroll
  for (int m = 0; m < 4; ++m) {
#pragma unroll
    for (int n = 0; n < 4; ++n) {
      const int ng = bx * 128 + wcol + n * 16 + (lane & 15);
      const int mg0 = by * 128 + wrow + m * 16 + (lane >> 4) * 4;
      if (MODE == 0) {
#pragma unroll
        for (int i = 0; i < 4; ++i) Cout[(size_t)(mg0 + i) * N + ng] = acc[m][n][i];
      } else {
        const int sec = ng >> 10;            // 0=Q 1=K 2=V (uniform per fragment)
        const int w = ng & 1023;
        const int h = w >> 6, d = w & 63;
        const int t0 = mg0 & (TT - 1);       // mg0 % 4 == 0 -> 4 consecutive t
        const int b = mg0 >> 11;
        const int bh = b * NH + h;
        if (sec == 0) {
#pragma unroll
          for (int i = 0; i < 4; ++i)
            Qo[((size_t)bh * TT + t0 + i) * DH + d] = f32_to_bf16u(acc[m][n][i] * QSCALE);
        } else if (sec == 1) {
#pragma unroll
          for (int i = 0; i < 4; ++i)
            Ko[((size_t)bh * TT + t0 + i) * DH + d] = f32_to_bf16u(acc[m][n][i]);
        } else {
          ushort4 o;
          o.x = f32_to_bf16u(acc[m][n][0]);
          o.y = f32_to_bf16u(acc[m][n][1]);
          o.z = f32_to_bf16u(acc[m][n][2]);
          o.w = f32_to_bf16u(acc[m][n][3]);
          *reinterpret_cast<ushort4*>(&Vo[((size_t)bh * DH + d) * TT + t0]) = o;  // V^T
        }
      }
    }
  }
}

// ---------------- flash attention v7 (FROZEN): cvt_pk P-pack ----------------
__global__ __launch_bounds__(256, 4) void attn_kernel(const ushort* __restrict__ Q,
                                                      const ushort* __restrict__ K,
                                                      const ushort* __restrict__ V,
                                                      ushort* __restrict__ O) {
  __shared__ __align__(16) ushort Ks[2][64 * 64];
  __shared__ __align__(16) ushort Vs[2][64 * 64];
  const int tid = threadIdx.x;
  const int lane = tid & 63, wid = tid >> 6;
  const int bh = blockIdx.x;
  const int q0 = blockIdx.y * 128 + wid * 32;
  const int qr = lane & 15, lg = lane >> 4;

  const ushort* Qh = Q + (size_t)bh * TT * DH;
  const ushort* Kh = K + (size_t)bh * TT * DH;
  const ushort* Vh = V + (size_t)bh * DH * TT;

  s16x8 qf[2][2];
#pragma unroll
  for (int qt = 0; qt < 2; ++qt)
#pragma unroll
    for (int h = 0; h < 2; ++h)
      qf[qt][h] = ld8(&Qh[(q0 + qt * 16 + qr) * DH + h * 32 + lg * 8]);

  const int pk = 8 * (qr >> 2) + (qr & 3);  // key-row permutation

  const uint one_bf = 0x3F803F80u;
  const s16x8 ONES = __builtin_bit_cast(s16x8, (uint4){one_bf, one_bf, one_bf, one_bf});

  f32x4 acc[2][4] = {};
  f32x4 acc1[2] = {};            // row-sum accumulator (denominator)

#define SWZ(r) ((r ^ ((r & 8) >> 1)) & 7)

  // hoisted LDS fragment offsets (fully unrolled -> registers, static indexing)
  int koff[2][2][2], voff[2][4];
#pragma unroll
  for (int kh = 0; kh < 2; ++kh) {
#pragma unroll
    for (int jj = 0; jj < 2; ++jj)
#pragma unroll
      for (int h = 0; h < 2; ++h) {
        const int r = kh * 32 + pk + 4 * jj;
        koff[kh][jj][h] = r * 64 + ((h * 4 + lg) ^ SWZ(r)) * 8;
      }
#pragma unroll
    for (int g = 0; g < 4; ++g) {
      const int r = g * 16 + qr;
      voff[kh][g] = r * 64 + ((kh * 4 + lg) ^ SWZ(r)) * 8;
    }
  }

  // stage 64-key K and V^T tiles; pre-swizzled global source, linear LDS dest
#define STAGE(buf, k0)                                                              \
  {                                                                                 \
    _Pragma("unroll") for (int j = 0; j < 2; ++j) {                                 \
      const int l = tid + 256 * j;                                                  \
      const int row = l >> 3, ch = l & 7;                                           \
      const int sc = ch ^ SWZ(row);                                                 \
      gload_lds16(&Kh[(size_t)((k0) + row) * DH + sc * 8],                          \
                  &Ks[buf][(wid * 64 + 256 * j) * 8]);                              \
      gload_lds16(&Vh[(size_t)row * TT + (k0) + sc * 8],                            \
                  &Vs[buf][(wid * 64 + 256 * j) * 8]);                              \
    }                                                                               \
  }

  STAGE(0, 0);
  __syncthreads();

  for (int t = 0; t < TT / 64; ++t) {
    const int buf = t & 1;
    if (t + 1 < TT / 64) STAGE(buf ^ 1, (t + 1) * 64);
    const ushort* Kb = Ks[buf];
    const ushort* Vb = Vs[buf];

#pragma unroll
    for (int kh = 0; kh < 2; ++kh) {
      s16x8 kf[2][2];
#pragma unroll
      for (int jj = 0; jj < 2; ++jj)
#pragma unroll
        for (int h = 0; h < 2; ++h) kf[jj][h] = ld8(&Kb[koff[kh][jj][h]]);
      s16x8 vf[4];
#pragma unroll
      for (int g = 0; g < 4; ++g) vf[g] = ld8(&Vb[voff[kh][g]]);

#pragma unroll
      for (int qt = 0; qt < 2; ++qt) {
        const f32x4 z = {};
        __builtin_amdgcn_s_setprio(1);
        f32x4 slo = mfma32(kf[0][0], qf[qt][0], z);
        slo = mfma32(kf[0][1], qf[qt][1], slo);
        f32x4 shi = mfma32(kf[1][0], qf[qt][0], z);
        shi = mfma32(kf[1][1], qf[qt][1], shi);
        __builtin_amdgcn_s_setprio(0);
        // lane: S[q=qr][phys key base + 8*lg + i] (slo) and +4 (shi)

        float p[8];
#pragma unroll
        for (int i = 0; i < 4; ++i) {
          p[i] = __builtin_amdgcn_exp2f(slo[i]);
          p[4 + i] = __builtin_amdgcn_exp2f(shi[i]);
        }

        // pack to bf16: v_cvt_pk_bf16_f32 (RNE), 1 op per pair
        uint u[4];
#pragma unroll
        for (int e = 0; e < 4; ++e)
          asm("v_cvt_pk_bf16_f32 %0, %1, %2" : "=v"(u[e]) : "v"(p[2 * e]), "v"(p[2 * e + 1]));
        const s16x8 pa = __builtin_bit_cast(s16x8, u);

        __builtin_amdgcn_s_setprio(1);
#pragma unroll
        for (int g = 0; g < 4; ++g) acc[qt][g] = mfma32(pa, vf[g], acc[qt][g]);
        acc1[qt] = mfma32(pa, ONES, acc1[qt]);  // denominator row-sum
        __builtin_amdgcn_s_setprio(0);
      }
    }
    __syncthreads();
  }

  const int b = bh >> 4, h = bh & 15;
#pragma unroll
  for (int qt = 0; qt < 2; ++qt) {
    float inv[4];
#pragma unroll
    for (int i = 0; i < 4; ++i) inv[i] = 1.0f / acc1[qt][i];
#pragma unroll
    for (int g = 0; g < 4; ++g) {
#pragma unroll
      for (int i = 0; i < 4; ++i) {
        const int tq = q0 + qt * 16 + lg * 4 + i;
        const int col = h * DH + g * 16 + qr;
        O[((size_t)b * TT + tq) * TC + col] = f32_to_bf16u(acc[qt][g][i] * inv[i]);
      }
    }
  }
#undef STAGE
#undef SWZ
}

// ---------------- launch ----------------
extern "C" void kernel_launch(void* const* d_in, const int* in_sizes, int n_in,
                              void* d_out, int out_size, void* d_ws, size_t ws_size,
                              hipStream_t stream) {
  const float* x = (const float*)d_in[0];
  const float* wqkv = (const float*)d_in[1];
  const float* wout = (const float*)d_in[2];
  float* out = (float*)d_out;
  char* ws = (char*)d_ws;

  // workspace layout (72 MB total); xb is dead after GEMM1 so attn output reuses it
  ushort* xb    = (ushort*)(ws);                        // 16 MB, later attn_out
  ushort* wqkvb = (ushort*)(ws + ((size_t)16 << 20));   // 6 MB
  ushort* woutb = (ushort*)(ws + ((size_t)22 << 20));   // 2 MB
  ushort* qb    = (ushort*)(ws + ((size_t)24 << 20));   // 16 MB
  ushort* kb    = (ushort*)(ws + ((size_t)40 << 20));   // 16 MB
  ushort* vtb   = (ushort*)(ws + ((size_t)56 << 20));   // 16 MB

  cvt3_kernel<<<2048, 256, 0, stream>>>(x, xb, MROWS * TC / 4,
                                        wqkv, wqkvb, 3 * TC * TC / 4,
                                        wout, woutb, TC * TC / 4);

  gemm_bt<1><<<dim3(3 * TC / 128, MROWS / 128), 256, 0, stream>>>(
      xb, wqkvb, nullptr, qb, kb, vtb, 3 * TC);

  attn_kernel<<<dim3(NB * NH, TT / 128), 256, 0, stream>>>(qb, kb, vtb, xb);

  gemm_bt<0><<<dim3(TC / 128, MROWS / 128), 256, 0, stream>>>(
      xb, woutb, out, nullptr, nullptr, nullptr, TC);
}